// Round 1
// baseline (3698.264 us; speedup 1.0000x reference)
//
#include <hip/hip_runtime.h>
#include <hip/hip_cooperative_groups.h>

namespace cg = cooperative_groups;

#define DI __device__ __forceinline__

DI float sigm(float x)   { return 1.0f / (1.0f + __expf(-x)); }
DI float tanhf_(float x) { return 2.0f / (1.0f + __expf(-2.0f * x)) - 1.0f; }

// ---------------- conv1: [1024,64,64,3] -> [1024,31,31,32], k4 s2 VALID, relu ----
__global__ void conv1_k(const float* __restrict__ in, const float* __restrict__ w,
                        const float* __restrict__ bias, float* __restrict__ out) {
  int idx = blockIdx.x * 256 + threadIdx.x;
  if (idx >= 1024 * 31 * 31 * 32) return;
  int c = idx & 31;
  int t = idx >> 5;
  int x = t % 31; t /= 31;
  int y = t % 31; t /= 31;
  int n = t;
  const float* ip = in + (((size_t)n * 64 + 2 * y) * 64 + 2 * x) * 3;
  float acc = bias[c];
#pragma unroll
  for (int ky = 0; ky < 4; ++ky)
#pragma unroll
    for (int kx = 0; kx < 4; ++kx)
#pragma unroll
      for (int ci = 0; ci < 3; ++ci)
        acc += ip[(ky * 64 + kx) * 3 + ci] * w[((ky * 4 + kx) * 3 + ci) * 32 + c];
  out[idx] = fmaxf(acc, 0.0f);
}

// ---- generic k4 s2 VALID conv, register-blocked 2x (x) * 2 (c), relu ----
// thread -> outputs (n, y, x0..x0+1, c & c+COUT/2)
template <int CIN, int COUT, int WIN, int WOUT>
__global__ void conv_blk(const float* __restrict__ in, const float* __restrict__ w,
                         const float* __restrict__ bias, float* __restrict__ out,
                         int img_stride) {
  constexpr int CH = COUT / 2;
  constexpr int XP = WOUT / 2;
  int idx = blockIdx.x * 256 + threadIdx.x;
  if (idx >= 1024 * WOUT * XP * CH) return;
  int c = idx % CH; int t = idx / CH;
  int xp = t % XP;  t /= XP;
  int y = t % WOUT; t /= WOUT;
  int n = t;
  const float* ip = in + (((size_t)n * WIN + 2 * y) * WIN + 4 * xp) * CIN;
  float b0v = bias[c], b1v = bias[c + CH];
  float a00 = b0v, a01 = b1v, a10 = b0v, a11 = b1v;
#pragma unroll
  for (int ky = 0; ky < 4; ++ky) {
#pragma unroll
    for (int kx = 0; kx < 4; ++kx) {
      const float* ipr = ip + (ky * WIN + kx) * CIN;
      const float* wp  = w + ((ky * 4 + kx) * CIN) * COUT + c;
#pragma unroll 8
      for (int ci = 0; ci < CIN; ++ci) {
        float w0 = wp[(size_t)ci * COUT], w1 = wp[(size_t)ci * COUT + CH];
        float i0 = ipr[ci], i1 = ipr[2 * CIN + ci];
        a00 += i0 * w0; a01 += i0 * w1;
        a10 += i1 * w0; a11 += i1 * w1;
      }
    }
  }
  int x0 = 2 * xp;
  float* op = out + (size_t)n * img_stride + ((size_t)y * WOUT + x0) * COUT;
  op[c]           = fmaxf(a00, 0.0f);
  op[c + CH]      = fmaxf(a01, 0.0f);
  op[COUT + c]    = fmaxf(a10, 0.0f);
  op[COUT + c+CH] = fmaxf(a11, 0.0f);
}

// ---- copy actions into xin columns 1024..1025 (row length 1026) ----
__global__ void act_copy(const float* __restrict__ act, float* __restrict__ xin) {
  int i = blockIdx.x * 256 + threadIdx.x;
  if (i < 2048) xin[(size_t)(i >> 1) * 1026 + 1024 + (i & 1)] = act[i];
}

// ---- xpart[t][b][2048] = xin[b*64+t][0..1026) @ k_l1[0..1026) + b_l1 ----
__global__ void gemm_xpart(const float* __restrict__ A, const float* __restrict__ Bw,
                           const float* __restrict__ bias, float* __restrict__ C) {
  __shared__ float As[16][64];
  __shared__ float Bs[16][64];
  const int tid = threadIdx.x;
  const int tx = tid & 15, ty = tid >> 4;
  const int m0 = blockIdx.y * 64, n0 = blockIdx.x * 64;
  float acc[4][4] = {};
  for (int k0 = 0; k0 < 1026; k0 += 16) {
#pragma unroll
    for (int i = 0; i < 4; ++i) {
      int lin = tid + i * 256;
      int ka = lin & 15, mm = lin >> 4;
      As[ka][mm] = (k0 + ka < 1026) ? A[(size_t)(m0 + mm) * 1026 + k0 + ka] : 0.0f;
      int kb = lin >> 6, nn = lin & 63;
      Bs[kb][nn] = (k0 + kb < 1026) ? Bw[(size_t)(k0 + kb) * 2048 + n0 + nn] : 0.0f;
    }
    __syncthreads();
#pragma unroll
    for (int kk = 0; kk < 16; ++kk) {
      float av[4], bv[4];
#pragma unroll
      for (int i = 0; i < 4; ++i) { av[i] = As[kk][ty * 4 + i]; bv[i] = Bs[kk][tx * 4 + i]; }
#pragma unroll
      for (int i = 0; i < 4; ++i)
#pragma unroll
        for (int j = 0; j < 4; ++j) acc[i][j] += av[i] * bv[j];
    }
    __syncthreads();
  }
#pragma unroll
  for (int i = 0; i < 4; ++i) {
    int m = m0 + ty * 4 + i;
    int xrow = (m & 63) * 16 + (m >> 6);   // (t, b)
#pragma unroll
    for (int j = 0; j < 4; ++j) {
      int n = n0 + tx * 4 + j;
      C[(size_t)xrow * 2048 + n] = acc[i][j] + bias[n];
    }
  }
}

// ---- persistent 2-layer LSTM over T=64, cooperative grid, 1 grid.sync per step ----
// grid: 32 blocks x 512 thr. block = (bgrp = blk>>2 -> batch pair, uch = blk&3 -> col chunk)
// layer1: thread (u = uch*128 + tid&127, ks = tid>>7 of 4) : 2 batch x 4 gates, K-slice 128
// layer2: thread (u = uch*64  + tid&63,  ks = tid>>6 of 8) : 2 batch x 4 gates, K-slice 96
__global__ void __launch_bounds__(512, 1)
lstm_k(const float* __restrict__ xpart,   // [64][16][2048] (incl b_l1)
       const float* __restrict__ kl1,     // [1538][2048]
       const float* __restrict__ kl2,     // [768][1024]
       const float* __restrict__ bl2,     // [1024]
       float* __restrict__ h1b,           // [2][16][512]
       float* __restrict__ c1,            // [16][512]
       float* __restrict__ h2b,           // [2][16][256]
       float* __restrict__ c2,            // [16][256]
       float* __restrict__ out_seq) {     // [16][64][256]
  cg::grid_group grid = cg::this_grid();
  __shared__ float stg[1536];
  __shared__ float red[3584];
  const int tid  = threadIdx.x;
  const int bgrp = blockIdx.x >> 2;
  const int uch  = blockIdx.x & 3;
  const int b0   = bgrp * 2;
  const float* Wh1 = kl1 + (size_t)1026 * 2048;

  const int laneA = tid & 127, ksA = tid >> 7;
  const int uA = uch * 128 + laneA;
  const int laneB = tid & 63,  ksB = tid >> 6;
  const int uB = uch * 64 + laneB;

  for (int t = 0; t < 64; ++t) {
    const float* h1c = h1b + (size_t)(t & 1) * 8192;
    float* h1n       = h1b + (size_t)((t + 1) & 1) * 8192;
    const float* h2c = h2b + (size_t)(t & 1) * 4096;
    float* h2n       = h2b + (size_t)((t + 1) & 1) * 4096;

    // -------- layer 1 --------
    __syncthreads();                               // protect LDS reuse from prev iter
    for (int i = tid; i < 1024; i += 512) stg[i] = h1c[b0 * 512 + i];
    __syncthreads();
    float acc[8] = {0, 0, 0, 0, 0, 0, 0, 0};
    {
      const int kend = ksA * 128 + 128;
#pragma unroll 4
      for (int k = ksA * 128; k < kend; ++k) {
        const float* wr = Wh1 + (size_t)k * 2048 + uA;
        float wi = wr[0], wj = wr[512], wf = wr[1024], wo = wr[1536];
        float ha = stg[k], hb = stg[512 + k];
        acc[0] += ha * wi; acc[1] += ha * wj; acc[2] += ha * wf; acc[3] += ha * wo;
        acc[4] += hb * wi; acc[5] += hb * wj; acc[6] += hb * wf; acc[7] += hb * wo;
      }
    }
    if (ksA > 0) {
      float* r = red + ((size_t)(ksA - 1) * 128 + laneA) * 8;
#pragma unroll
      for (int j = 0; j < 8; ++j) r[j] = acc[j];
    }
    __syncthreads();
    if (ksA == 0) {
#pragma unroll
      for (int p = 0; p < 3; ++p) {
        const float* r = red + ((size_t)p * 128 + laneA) * 8;
#pragma unroll
        for (int j = 0; j < 8; ++j) acc[j] += r[j];
      }
#pragma unroll
      for (int bb = 0; bb < 2; ++bb) {
        int b = b0 + bb;
        const float* xp = xpart + ((size_t)t * 16 + b) * 2048 + uA;
        float gi = acc[bb * 4 + 0] + xp[0];
        float gj = acc[bb * 4 + 1] + xp[512];
        float gf = acc[bb * 4 + 2] + xp[1024];
        float go = acc[bb * 4 + 3] + xp[1536];
        float cold = c1[b * 512 + uA];
        float cn = sigm(gf + 1.0f) * cold + sigm(gi) * tanhf_(gj);
        float hn = sigm(go) * tanhf_(cn);
        c1[b * 512 + uA] = cn;
        h1n[b * 512 + uA] = hn;
      }
    }
    grid.sync();   // the ONLY grid sync per step: publishes h1n (and orders h2/out across steps)

    // -------- layer 2 --------
    for (int i = tid; i < 1536; i += 512) {
      int bb = i / 768, k = i - bb * 768;
      stg[i] = (k < 512) ? h1n[(b0 + bb) * 512 + k] : h2c[(b0 + bb) * 256 + (k - 512)];
    }
    __syncthreads();
    float accB[8] = {0, 0, 0, 0, 0, 0, 0, 0};
    {
      const int kend = ksB * 96 + 96;
#pragma unroll 4
      for (int k = ksB * 96; k < kend; ++k) {
        const float* wr = kl2 + (size_t)k * 1024 + uB;
        float wi = wr[0], wj = wr[256], wf = wr[512], wo = wr[768];
        float ha = stg[k], hb = stg[768 + k];
        accB[0] += ha * wi; accB[1] += ha * wj; accB[2] += ha * wf; accB[3] += ha * wo;
        accB[4] += hb * wi; accB[5] += hb * wj; accB[6] += hb * wf; accB[7] += hb * wo;
      }
    }
    if (ksB > 0) {
      float* r = red + ((size_t)(ksB - 1) * 64 + laneB) * 8;
#pragma unroll
      for (int j = 0; j < 8; ++j) r[j] = accB[j];
    }
    __syncthreads();
    if (ksB == 0) {
#pragma unroll
      for (int p = 0; p < 7; ++p) {
        const float* r = red + ((size_t)p * 64 + laneB) * 8;
#pragma unroll
        for (int j = 0; j < 8; ++j) accB[j] += r[j];
      }
#pragma unroll
      for (int bb = 0; bb < 2; ++bb) {
        int b = b0 + bb;
        float gi = accB[bb * 4 + 0] + bl2[uB];
        float gj = accB[bb * 4 + 1] + bl2[256 + uB];
        float gf = accB[bb * 4 + 2] + bl2[512 + uB];
        float go = accB[bb * 4 + 3] + bl2[768 + uB];
        float cold = c2[b * 256 + uB];
        float cn = sigm(gf + 1.0f) * cold + sigm(gi) * tanhf_(gj);
        float hn = sigm(go) * tanhf_(cn);
        c2[b * 256 + uB] = cn;
        h2n[b * 256 + uB] = hn;
        out_seq[((size_t)b * 64 + t) * 256 + uB] = hn;
      }
    }
    // no grid.sync here: layer1(t+1) touches only h1 buffers / c1; proven disjoint
    // from layer2(t)'s h2/out writes. Next step's mid-sync orders h2n for layer2(t+1).
  }
}

// ---- dense head: relu(lstm_out @ wd1 + bd1) @ wd2 + bd2 -> [1024] ----
__global__ void head_k(const float* __restrict__ xin, const float* __restrict__ wd1,
                       const float* __restrict__ bd1, const float* __restrict__ wd2,
                       const float* __restrict__ bd2, float* __restrict__ out) {
  __shared__ float xs[4][256];
  __shared__ float ps[4][128];
  int r0 = blockIdx.x * 4;
  int tid = threadIdx.x;
  for (int i = tid; i < 1024; i += 128) xs[i >> 8][i & 255] = xin[(size_t)r0 * 256 + i];
  __syncthreads();
  float w2 = wd2[tid];
  float bb = bd1[tid];
#pragma unroll
  for (int rr = 0; rr < 4; ++rr) {
    float acc = bb;
#pragma unroll 8
    for (int k = 0; k < 256; ++k) acc += xs[rr][k] * wd1[k * 128 + tid];
    ps[rr][tid] = fmaxf(acc, 0.0f) * w2;
  }
  __syncthreads();
  if (tid < 4) {
    float s = bd2[0];
    for (int k = 0; k < 128; ++k) s += ps[tid][k];
    out[r0 + tid] = s;
  }
}

extern "C" void kernel_launch(void* const* d_in, const int* in_sizes, int n_in,
                              void* d_out, int out_size, void* d_ws, size_t ws_size,
                              hipStream_t stream) {
  const float* frames  = (const float*)d_in[0];
  const float* actions = (const float*)d_in[1];
  const float* w1 = (const float*)d_in[2];   const float* b1 = (const float*)d_in[3];
  const float* w2 = (const float*)d_in[4];   const float* b2 = (const float*)d_in[5];
  const float* w3 = (const float*)d_in[6];   const float* b3 = (const float*)d_in[7];
  const float* w4 = (const float*)d_in[8];   const float* b4 = (const float*)d_in[9];
  const float* kl1 = (const float*)d_in[10]; const float* bl1 = (const float*)d_in[11];
  const float* kl2 = (const float*)d_in[12]; const float* bl2 = (const float*)d_in[13];
  const float* wd1 = (const float*)d_in[14]; const float* bd1 = (const float*)d_in[15];
  const float* wd2 = (const float*)d_in[16]; const float* bd2 = (const float*)d_in[17];
  float* out = (float*)d_out;

  float* ws = (float*)d_ws;
  // overlayed layout (floats): a1[31.49M] | a2[12.85M] ; a3 overlays a1, xin overlays a2
  float* a1    = ws;                 // [1024][31][31][32]
  float* a2    = ws + 31490048u;     // [1024][14][14][64]
  float* a3    = ws;                 // [1024][6][6][128]   (a1 dead)
  float* xin   = ws + 31490048u;     // [1024][1026]        (a2 dead)
  float* xpart = ws + 44335104u;     // [64][16][2048]
  float* h1b   = ws + 46432256u;     // [2][16][512]
  float* c1    = ws + 46448640u;     // [16][512]
  float* h2b   = ws + 46456832u;     // [2][16][256]
  float* c2    = ws + 46465024u;     // [16][256]
  float* lout  = ws + 46469120u;     // [16][64][256]
  // end: 47,517,696 floats = ~181 MB

  hipMemsetAsync(h1b, 0, (16384 + 8192 + 8192 + 4096) * sizeof(float), stream);

  conv1_k<<<123008, 256, 0, stream>>>(frames, w1, b1, a1);
  conv_blk<32, 64, 31, 14><<<12544, 256, 0, stream>>>(a1, w2, b2, a2, 14 * 14 * 64);
  conv_blk<64, 128, 14, 6><<<4608, 256, 0, stream>>>(a2, w3, b3, a3, 6 * 6 * 128);
  conv_blk<128, 256, 6, 2><<<1024, 256, 0, stream>>>(a3, w4, b4, xin, 1026);
  act_copy<<<8, 256, 0, stream>>>(actions, xin);
  gemm_xpart<<<dim3(32, 16), 256, 0, stream>>>(xin, kl1, bl1, xpart);

  void* args[9];
  args[0] = (void*)&xpart; args[1] = (void*)&kl1; args[2] = (void*)&kl2; args[3] = (void*)&bl2;
  args[4] = (void*)&h1b;   args[5] = (void*)&c1;  args[6] = (void*)&h2b; args[7] = (void*)&c2;
  args[8] = (void*)&lout;
  hipLaunchCooperativeKernel((void*)lstm_k, dim3(32), dim3(512), args, 0, stream);

  head_k<<<256, 128, 0, stream>>>(lout, wd1, bd1, wd2, bd2, out);
}